// Round 1
// baseline (1496.833 us; speedup 1.0000x reference)
//
#include <hip/hip_runtime.h>
#include <hip/hip_bf16.h>

// RNN: emb[x] -> xw GEMM -> 256 sequential tanh steps -> FC.
// All matmuls in f16 MFMA (16x16x32) with f32 accumulate.
// B=64, T=256, H=E=512, O=4.

typedef _Float16 f16;
typedef _Float16 f16x4 __attribute__((ext_vector_type(4)));
typedef _Float16 f16x8 __attribute__((ext_vector_type(8)));
typedef float    f32x4 __attribute__((ext_vector_type(4)));

#define BSZ 64
#define TSZ 256
#define HSZ 512

// d_ws layout (bytes)
#define XWB_OFF   0u
#define XWB_BYTES (64u*256u*512u*2u)            // 16 MB: xw + b_ih + b_hh, f16 [B*T][H]
#define AWHH_OFF  (XWB_OFF + XWB_BYTES)         // 512 KB: W_hh A-operand fragments
#define BWIH_OFF  (AWHH_OFF + 512u*1024u)       // 512 KB: W_ih B-operand fragments
#define HT_OFF    (BWIH_OFF + 512u*1024u)       // 128 KB: final hidden state f32 [B][H]

// ---------------------------------------------------------------------------
// K0: pack W_hh (A-operand layout) and W_ih (B-operand layout) into
// fragment-linear f16: frag (kc, tile) at ((kc*32 + tile)*64 + lane)*8 f16.
//   W_hh A-frag: A[m][k] = W_hh[m][k]   (row = m = tile*16 + (lane&15), col = k)
//   W_ih B-frag: B[k][n] = W_ih[n][k]   (row = n = tile*16 + (lane&15), col = k)
// Both gather 8 consecutive f32 from source row (lane&15), col block (lane>>4)*8.
// ---------------------------------------------------------------------------
__global__ __launch_bounds__(64) void k0_prep(const float* __restrict__ Whh,
                                              const float* __restrict__ Wih,
                                              f16* __restrict__ awhh,
                                              f16* __restrict__ bwih) {
    int id   = blockIdx.x;           // 0..1023
    int lane = threadIdx.x;          // 0..63
    bool is_ih = id >= 512;
    int lid = is_ih ? (id - 512) : id;       // = kc*32 + tile
    const float* src = is_ih ? Wih : Whh;
    f16* dst = is_ih ? bwih : awhh;
    int tile = lid & 31;
    int kc   = lid >> 5;
    int row  = tile * 16 + (lane & 15);
    int col0 = kc * 32 + (lane >> 4) * 8;
    const float* p = src + (size_t)row * 512 + col0;
    float4 v0 = *(const float4*)(p);
    float4 v1 = *(const float4*)(p + 4);
    f16x8 o;
    o[0] = (f16)v0.x; o[1] = (f16)v0.y; o[2] = (f16)v0.z; o[3] = (f16)v0.w;
    o[4] = (f16)v1.x; o[5] = (f16)v1.y; o[6] = (f16)v1.z; o[7] = (f16)v1.w;
    *(f16x8*)(dst + (size_t)lid * 512 + lane * 8) = o;
}

// ---------------------------------------------------------------------------
// K1: xwb[m][n] = sum_k emb[x[m]][k] * W_ih[n][k] + b_ih[n] + b_hh[n], f16 out.
// M = B*T = 16384 (grid 256 WGs x 64-row strip), N = 512 (full, 32 n-tiles per
// wave), K = 512 (16 chunks of 32). A gathered straight from emb (f32->f16),
// B staged per k-chunk into LDS from the packed fragments.
// ---------------------------------------------------------------------------
__global__ __launch_bounds__(256) void k1_xw(const int* __restrict__ x,
                                             const float* __restrict__ emb,
                                             const float* __restrict__ bih,
                                             const float* __restrict__ bhh,
                                             const f16* __restrict__ bwih,
                                             f16* __restrict__ xwb) {
    __shared__ f16 Bs[32 * 512];     // 32 KB: one k-chunk of B fragments
    int tid  = threadIdx.x;
    int wave = tid >> 6, lane = tid & 63;
    int quad = lane >> 4, l15 = lane & 15;
    int mrow0 = blockIdx.x * 64 + wave * 16;

    int arow_idx = x[mrow0 + l15];                  // gathered embedding row
    const float* arow = emb + (size_t)arow_idx * 512;

    f32x4 acc[32];
#pragma unroll
    for (int nt = 0; nt < 32; ++nt) acc[nt] = (f32x4){0.f, 0.f, 0.f, 0.f};

    for (int kc = 0; kc < 16; ++kc) {
        __syncthreads();   // protect previous iteration's LDS reads
        {   // stage 32 KB of B frags: contiguous copy
            const float4* s4 = (const float4*)(bwih + (size_t)kc * 16384);
            float4* d4 = (float4*)Bs;
#pragma unroll
            for (int q = 0; q < 8; ++q) d4[tid * 8 + q] = s4[tid * 8 + q];
        }
        __syncthreads();

        float4 a0 = *(const float4*)(arow + kc * 32 + quad * 8);
        float4 a1 = *(const float4*)(arow + kc * 32 + quad * 8 + 4);
        f16x8 af;
        af[0] = (f16)a0.x; af[1] = (f16)a0.y; af[2] = (f16)a0.z; af[3] = (f16)a0.w;
        af[4] = (f16)a1.x; af[5] = (f16)a1.y; af[6] = (f16)a1.z; af[7] = (f16)a1.w;

#pragma unroll
        for (int nt = 0; nt < 32; ++nt) {
            f16x8 bf = *(const f16x8*)(Bs + nt * 512 + lane * 8);
            acc[nt] = __builtin_amdgcn_mfma_f32_16x16x32_f16(af, bf, acc[nt], 0, 0, 0);
        }
    }

    // Epilogue: D col n = l15 (+16*nt), D row = quad*4 + r. Fold both biases.
#pragma unroll 4
    for (int nt = 0; nt < 32; ++nt) {
        int n = nt * 16 + l15;
        float bias = bih[n] + bhh[n];
#pragma unroll
        for (int r = 0; r < 4; ++r) {
            int m = mrow0 + quad * 4 + r;
            xwb[(size_t)m * 512 + n] = (f16)(acc[nt][r] + bias);
        }
    }
}

// ---------------------------------------------------------------------------
// K2: the recurrence. 16 WGs x 512 threads (8 waves, 2/SIMD); WG wg owns
// batches wg*4..wg*4+3 (cols 0..3 of the 16-wide N tile; cols 4..15 stay 0).
// Transposed GEMM per step: D[i][b] = sum_j W_hh[i][j] * h[b][j].
//   A = packed W_hh frags streamed from L2 (512 KB/step/WG),
//   B = h from LDS (double-buffered, one __syncthreads per step).
// Wave w owns m-tiles 4w..4w+3 (i-rows). Epilogue: + xwb, tanh, write h f16.
// ---------------------------------------------------------------------------
__global__ __launch_bounds__(512, 2) void k2_rnn(const f16* __restrict__ awhh,
                                                 const f16* __restrict__ xwb,
                                                 float* __restrict__ hT) {
    __shared__ f16 hb[2][16][520];   // [buf][batch-col][i], +8 pad, 33.3 KB
    int tid  = threadIdx.x;
    int wave = tid >> 6, lane = tid & 63;
    int quad = lane >> 4, n = lane & 15;
    int mtb  = wave * 4;
    int b    = blockIdx.x * 4 + n;   // valid only when n < 4

    for (int i = tid; i < 2 * 16 * 520; i += 512) ((f16*)hb)[i] = (f16)0.f;
    __syncthreads();

    for (int t = 0; t < 256; ++t) {
        const f16* hc = &hb[t & 1][0][0];
        f16*       hn = &hb[(t + 1) & 1][0][0];

        f32x4 acc[4];
#pragma unroll
        for (int p = 0; p < 4; ++p) acc[p] = (f32x4){0.f, 0.f, 0.f, 0.f};

#pragma unroll
        for (int kc = 0; kc < 16; ++kc) {
            f16x8 bf = *(const f16x8*)(hc + n * 520 + kc * 32 + quad * 8);
#pragma unroll
            for (int p = 0; p < 4; ++p) {
                f16x8 af = *(const f16x8*)(awhh +
                    ((size_t)(kc * 32 + mtb + p) * 64 + lane) * 8);
                acc[p] = __builtin_amdgcn_mfma_f32_16x16x32_f16(af, bf, acc[p], 0, 0, 0);
            }
        }

        if (n < 4) {
#pragma unroll
            for (int p = 0; p < 4; ++p) {
                int i0 = (mtb + p) * 16 + quad * 4;
                f16x4 xw4 = *(const f16x4*)(xwb + ((size_t)(b * 256 + t) * 512 + i0));
                f16x4 hv;
                f32x4 hf;
#pragma unroll
                for (int r = 0; r < 4; ++r) {
                    float z = acc[p][r] + (float)xw4[r];
                    float e = __expf(2.f * z);       // bounded: |z| <~ 12
                    float th = (e - 1.f) / (e + 1.f);
                    hv[r] = (f16)th;
                    hf[r] = th;
                }
                *(f16x4*)(hn + n * 520 + i0) = hv;
                if (t == 255) *(f32x4*)(hT + (size_t)b * 512 + i0) = hf;
            }
        }
        __syncthreads();   // h(t+1) fully written before next step reads it
    }
}

// ---------------------------------------------------------------------------
// K3: out[b][o] = sum_i hT[b][i] * W_fc[o][i] + b_fc[o].  64 WGs (one per b),
// 4 waves (one per o), 8 elems/lane + wave shuffle reduce.
// ---------------------------------------------------------------------------
__global__ __launch_bounds__(256) void k3_fc(const float* __restrict__ hT,
                                             const float* __restrict__ Wfc,
                                             const float* __restrict__ bfc,
                                             float* __restrict__ out) {
    int b = blockIdx.x;
    int o = threadIdx.x >> 6, lane = threadIdx.x & 63;
    float s = 0.f;
#pragma unroll
    for (int c = 0; c < 8; ++c) {
        int i = c * 64 + lane;
        s += hT[(size_t)b * 512 + i] * Wfc[(size_t)o * 512 + i];
    }
#pragma unroll
    for (int off = 32; off > 0; off >>= 1) s += __shfl_down(s, off, 64);
    if (lane == 0) out[b * 4 + o] = s + bfc[o];
}

extern "C" void kernel_launch(void* const* d_in, const int* in_sizes, int n_in,
                              void* d_out, int out_size, void* d_ws, size_t ws_size,
                              hipStream_t stream) {
    const int*   x   = (const int*)d_in[0];
    const float* emb = (const float*)d_in[1];
    const float* Wih = (const float*)d_in[2];
    const float* Whh = (const float*)d_in[3];
    const float* bih = (const float*)d_in[4];
    const float* bhh = (const float*)d_in[5];
    const float* Wfc = (const float*)d_in[6];
    const float* bfc = (const float*)d_in[7];
    float* out = (float*)d_out;

    char* ws = (char*)d_ws;
    f16*   xwb  = (f16*)(ws + XWB_OFF);
    f16*   awhh = (f16*)(ws + AWHH_OFF);
    f16*   bwih = (f16*)(ws + BWIH_OFF);
    float* hT   = (float*)(ws + HT_OFF);

    hipLaunchKernelGGL(k0_prep, dim3(1024), dim3(64),  0, stream, Whh, Wih, awhh, bwih);
    hipLaunchKernelGGL(k1_xw,   dim3(256),  dim3(256), 0, stream, x, emb, bih, bhh, bwih, xwb);
    hipLaunchKernelGGL(k2_rnn,  dim3(16),   dim3(512), 0, stream, awhh, xwb, hT);
    hipLaunchKernelGGL(k3_fc,   dim3(64),   dim3(256), 0, stream, hT, Wfc, bfc, out);
}

// Round 2
// 871.779 us; speedup vs baseline: 1.7170x; 1.7170x over previous
//
#include <hip/hip_runtime.h>
#include <hip/hip_bf16.h>

// RNN: emb[x] -> xw GEMM -> 256 sequential tanh steps -> FC.
// All matmuls in f16 MFMA (16x16x32) with f32 accumulate.
// B=64, T=256, H=E=512, O=4.
//
// R2 change: K2 makes W_hh resident. Per wave: kc 0..7 A-frags pinned in
// VGPRs (128 regs), kc 8..8+LKC-1 in LDS, rest streamed from L2 through a
// depth-3 register pipeline. xwb slice prefetched at step top.

typedef _Float16 f16;
typedef _Float16 f16x4 __attribute__((ext_vector_type(4)));
typedef _Float16 f16x8 __attribute__((ext_vector_type(8)));
typedef float    f32x4 __attribute__((ext_vector_type(4)));

#define BSZ 64
#define TSZ 256
#define HSZ 512

// d_ws layout (bytes)
#define XWB_OFF   0u
#define XWB_BYTES (64u*256u*512u*2u)            // 16 MB: xw + b_ih + b_hh, f16 [B*T][H]
#define AWHH_OFF  (XWB_OFF + XWB_BYTES)         // 512 KB: W_hh A-operand fragments
#define BWIH_OFF  (AWHH_OFF + 512u*1024u)       // 512 KB: W_ih B-operand fragments
#define HT_OFF    (BWIH_OFF + 512u*1024u)       // 128 KB: final hidden state f32 [B][H]

// ---------------------------------------------------------------------------
// K0: pack W_hh (A-operand layout) and W_ih (B-operand layout) into
// fragment-linear f16: frag (kc, tile) at ((kc*32 + tile)*64 + lane)*8 f16.
// ---------------------------------------------------------------------------
__global__ __launch_bounds__(64) void k0_prep(const float* __restrict__ Whh,
                                              const float* __restrict__ Wih,
                                              f16* __restrict__ awhh,
                                              f16* __restrict__ bwih) {
    int id   = blockIdx.x;           // 0..1023
    int lane = threadIdx.x;          // 0..63
    bool is_ih = id >= 512;
    int lid = is_ih ? (id - 512) : id;       // = kc*32 + tile
    const float* src = is_ih ? Wih : Whh;
    f16* dst = is_ih ? bwih : awhh;
    int tile = lid & 31;
    int kc   = lid >> 5;
    int row  = tile * 16 + (lane & 15);
    int col0 = kc * 32 + (lane >> 4) * 8;
    const float* p = src + (size_t)row * 512 + col0;
    float4 v0 = *(const float4*)(p);
    float4 v1 = *(const float4*)(p + 4);
    f16x8 o;
    o[0] = (f16)v0.x; o[1] = (f16)v0.y; o[2] = (f16)v0.z; o[3] = (f16)v0.w;
    o[4] = (f16)v1.x; o[5] = (f16)v1.y; o[6] = (f16)v1.z; o[7] = (f16)v1.w;
    *(f16x8*)(dst + (size_t)lid * 512 + lane * 8) = o;
}

// ---------------------------------------------------------------------------
// K1: xwb[m][n] = sum_k emb[x[m]][k] * W_ih[n][k] + b_ih[n] + b_hh[n], f16.
// ---------------------------------------------------------------------------
__global__ __launch_bounds__(256) void k1_xw(const int* __restrict__ x,
                                             const float* __restrict__ emb,
                                             const float* __restrict__ bih,
                                             const float* __restrict__ bhh,
                                             const f16* __restrict__ bwih,
                                             f16* __restrict__ xwb) {
    __shared__ f16 Bs[32 * 512];     // 32 KB: one k-chunk of B fragments
    int tid  = threadIdx.x;
    int wave = tid >> 6, lane = tid & 63;
    int quad = lane >> 4, l15 = lane & 15;
    int mrow0 = blockIdx.x * 64 + wave * 16;

    int arow_idx = x[mrow0 + l15];                  // gathered embedding row
    const float* arow = emb + (size_t)arow_idx * 512;

    f32x4 acc[32];
#pragma unroll
    for (int nt = 0; nt < 32; ++nt) acc[nt] = (f32x4){0.f, 0.f, 0.f, 0.f};

    for (int kc = 0; kc < 16; ++kc) {
        __syncthreads();   // protect previous iteration's LDS reads
        {   // stage 32 KB of B frags: contiguous copy
            const float4* s4 = (const float4*)(bwih + (size_t)kc * 16384);
            float4* d4 = (float4*)Bs;
#pragma unroll
            for (int q = 0; q < 8; ++q) d4[tid * 8 + q] = s4[tid * 8 + q];
        }
        __syncthreads();

        float4 a0 = *(const float4*)(arow + kc * 32 + quad * 8);
        float4 a1 = *(const float4*)(arow + kc * 32 + quad * 8 + 4);
        f16x8 af;
        af[0] = (f16)a0.x; af[1] = (f16)a0.y; af[2] = (f16)a0.z; af[3] = (f16)a0.w;
        af[4] = (f16)a1.x; af[5] = (f16)a1.y; af[6] = (f16)a1.z; af[7] = (f16)a1.w;

#pragma unroll
        for (int nt = 0; nt < 32; ++nt) {
            f16x8 bf = *(const f16x8*)(Bs + nt * 512 + lane * 8);
            acc[nt] = __builtin_amdgcn_mfma_f32_16x16x32_f16(af, bf, acc[nt], 0, 0, 0);
        }
    }

    // Epilogue: D col n = l15 (+16*nt), D row = quad*4 + r. Fold both biases.
#pragma unroll 4
    for (int nt = 0; nt < 32; ++nt) {
        int n = nt * 16 + l15;
        float bias = bih[n] + bhh[n];
#pragma unroll
        for (int r = 0; r < 4; ++r) {
            int m = mrow0 + quad * 4 + r;
            xwb[(size_t)m * 512 + n] = (f16)(acc[nt][r] + bias);
        }
    }
}

// ---------------------------------------------------------------------------
// K2: the recurrence. 16 WGs x 512 threads; WG wg owns batches wg*4..wg*4+3.
// Per step: D[i][b] = sum_j W_hh[i][j] * h[b][j]; + xwb; tanh.
// Wave w owns m-tiles 4w..4w+3. W_hh residency:
//   kc 0..7          -> VGPR-persistent areg[4][8] (128 regs/lane)
//   kc 8..8+LKC-1    -> LDS fragS (32 KB per kc)
//   kc 8+LKC..15     -> streamed from L2, depth-3 register pipeline
// h double-buffered in LDS, stride 544 f16 (2-way bank alias = free).
// ---------------------------------------------------------------------------
template<int LKC>
__global__ __launch_bounds__(512, 2) void k2_rnn(const f16* __restrict__ awhh,
                                                 const f16* __restrict__ xwb,
                                                 float* __restrict__ hT) {
    constexpr int SKC = 8 - LKC;                 // streamed kc count
    extern __shared__ char smem[];
    f16* fragS = (f16*)smem;                               // 32 KB * LKC
    f16* hbuf  = (f16*)(smem + (size_t)32768 * LKC);       // 2*4*544 f16 = 8704 B

    int tid  = threadIdx.x;
    int wave = tid >> 6, lane = tid & 63;
    int quad = lane >> 4, n = lane & 15;
    int mtb  = wave * 4;
    int b    = blockIdx.x * 4 + n;               // valid only when n < 4

    // --- persistent A-frags, kc 0..7 ---
    f16x8 areg[4][8];
#pragma unroll
    for (int p = 0; p < 4; ++p)
#pragma unroll
        for (int kc = 0; kc < 8; ++kc)
            areg[p][kc] = *(const f16x8*)(awhh +
                ((size_t)(kc * 32 + mtb + p) * 64 + lane) * 8);

    // --- LDS-resident frags, kc 8..8+LKC-1 (per-wave private region) ---
#pragma unroll
    for (int p = 0; p < 4; ++p)
#pragma unroll
        for (int j = 0; j < LKC; ++j) {
            f16x8 v = *(const f16x8*)(awhh +
                ((size_t)((8 + j) * 32 + mtb + p) * 64 + lane) * 8);
            *(f16x8*)(fragS + (((mtb + p) * LKC + j) * 64 + lane) * 8) = v;
        }

    // --- zero h double-buffer ---
    {
        unsigned int* hz = (unsigned int*)hbuf;
        for (int i = tid; i < 2176; i += 512) hz[i] = 0u;
    }
    __syncthreads();

    const f16* xwb_b = xwb + (size_t)b * 256 * 512;   // deref'd only when n<4

    for (int t = 0; t < 256; ++t) {
        const f16* hc = hbuf + (size_t)(t & 1) * 4 * 544;
        f16*       hn = hbuf + (size_t)((t + 1) & 1) * 4 * 544;

        // prefetch xw for this step (h-independent -> latency hidden by MFMAs)
        f16x4 xw4[4];
        if (n < 4) {
#pragma unroll
            for (int p = 0; p < 4; ++p)
                xw4[p] = *(const f16x4*)(xwb_b + (size_t)t * 512 +
                                         (mtb + p) * 16 + quad * 4);
        }

        // streamed A-frag pipeline: prime 3 kc-groups
        f16x8 sbuf[3][4];
#pragma unroll
        for (int q = 0; q < (SKC < 3 ? SKC : 3); ++q)
#pragma unroll
            for (int p = 0; p < 4; ++p)
                sbuf[q % 3][p] = *(const f16x8*)(awhh +
                    ((size_t)((8 + LKC + q) * 32 + mtb + p) * 64 + lane) * 8);

        f32x4 acc[4];
#pragma unroll
        for (int p = 0; p < 4; ++p) acc[p] = (f32x4){0.f, 0.f, 0.f, 0.f};

#pragma unroll
        for (int kc = 0; kc < 16; ++kc) {
            f16x8 bf = {};
            if (n < 4)
                bf = *(const f16x8*)(hc + n * 544 + kc * 32 + quad * 8);

            if (kc < 8) {
#pragma unroll
                for (int p = 0; p < 4; ++p)
                    acc[p] = __builtin_amdgcn_mfma_f32_16x16x32_f16(
                        areg[p][kc], bf, acc[p], 0, 0, 0);
            } else if (kc < 8 + LKC) {
                int j = kc - 8;
#pragma unroll
                for (int p = 0; p < 4; ++p) {
                    f16x8 af = *(const f16x8*)(fragS +
                        (((mtb + p) * LKC + j) * 64 + lane) * 8);
                    acc[p] = __builtin_amdgcn_mfma_f32_16x16x32_f16(
                        af, bf, acc[p], 0, 0, 0);
                }
            } else {
                int q = kc - 8 - LKC;
#pragma unroll
                for (int p = 0; p < 4; ++p)
                    acc[p] = __builtin_amdgcn_mfma_f32_16x16x32_f16(
                        sbuf[q % 3][p], bf, acc[p], 0, 0, 0);
                if (q + 3 < SKC) {
#pragma unroll
                    for (int p = 0; p < 4; ++p)
                        sbuf[(q + 3) % 3][p] = *(const f16x8*)(awhh +
                            ((size_t)((8 + LKC + q + 3) * 32 + mtb + p) * 64 + lane) * 8);
                }
            }
        }

        if (n < 4) {
#pragma unroll
            for (int p = 0; p < 4; ++p) {
                int i0 = (mtb + p) * 16 + quad * 4;
                f16x4 hv;
                f32x4 hf;
#pragma unroll
                for (int r = 0; r < 4; ++r) {
                    float z = acc[p][r] + (float)xw4[p][r];
                    float e = __expf(2.f * z);       // bounded: |z| small
                    float th = (e - 1.f) / (e + 1.f);
                    hv[r] = (f16)th;
                    hf[r] = th;
                }
                *(f16x4*)(hn + n * 544 + i0) = hv;
                if (t == 255) *(f32x4*)(hT + (size_t)b * 512 + i0) = hf;
            }
        }
        __syncthreads();   // h(t+1) fully written before next step reads it
    }
}

// ---------------------------------------------------------------------------
// K3: out[b][o] = sum_i hT[b][i] * W_fc[o][i] + b_fc[o].
// ---------------------------------------------------------------------------
__global__ __launch_bounds__(256) void k3_fc(const float* __restrict__ hT,
                                             const float* __restrict__ Wfc,
                                             const float* __restrict__ bfc,
                                             float* __restrict__ out) {
    int b = blockIdx.x;
    int o = threadIdx.x >> 6, lane = threadIdx.x & 63;
    float s = 0.f;
#pragma unroll
    for (int c = 0; c < 8; ++c) {
        int i = c * 64 + lane;
        s += hT[(size_t)b * 512 + i] * Wfc[(size_t)o * 512 + i];
    }
#pragma unroll
    for (int off = 32; off > 0; off >>= 1) s += __shfl_down(s, off, 64);
    if (lane == 0) out[b * 4 + o] = s + bfc[o];
}

extern "C" void kernel_launch(void* const* d_in, const int* in_sizes, int n_in,
                              void* d_out, int out_size, void* d_ws, size_t ws_size,
                              hipStream_t stream) {
    const int*   x   = (const int*)d_in[0];
    const float* emb = (const float*)d_in[1];
    const float* Wih = (const float*)d_in[2];
    const float* Whh = (const float*)d_in[3];
    const float* bih = (const float*)d_in[4];
    const float* bhh = (const float*)d_in[5];
    const float* Wfc = (const float*)d_in[6];
    const float* bfc = (const float*)d_in[7];
    float* out = (float*)d_out;

    char* ws = (char*)d_ws;
    f16*   xwb  = (f16*)(ws + XWB_OFF);
    f16*   awhh = (f16*)(ws + AWHH_OFF);
    f16*   bwih = (f16*)(ws + BWIH_OFF);
    float* hT   = (float*)(ws + HT_OFF);

    hipLaunchKernelGGL(k0_prep, dim3(1024), dim3(64),  0, stream, Whh, Wih, awhh, bwih);
    hipLaunchKernelGGL(k1_xw,   dim3(256),  dim3(256), 0, stream, x, emb, bih, bhh, bwih, xwb);

    // K2: pick big-LDS variant (kc 8..11 resident, 139776 B) if the device
    // allows >64 KB per workgroup; else 64-KB-safe fallback (kc 8 only).
    const int LDS_BIG   = 32768 * 4 + 8704;   // 139776
    const int LDS_SMALL = 32768 * 1 + 8704;   // 41472
    int dev = 0;
    (void)hipGetDevice(&dev);
    int maxlds = 0;
    (void)hipDeviceGetAttribute(&maxlds, hipDeviceAttributeMaxSharedMemoryPerBlock, dev);
    bool big = maxlds >= LDS_BIG;
    if (big)
        big = (hipFuncSetAttribute((const void*)&k2_rnn<4>,
                                   hipFuncAttributeMaxDynamicSharedMemorySize,
                                   LDS_BIG) == hipSuccess);
    if (big) {
        hipLaunchKernelGGL(k2_rnn<4>, dim3(16), dim3(512), LDS_BIG, stream, awhh, xwb, hT);
    } else {
        hipLaunchKernelGGL(k2_rnn<1>, dim3(16), dim3(512), LDS_SMALL, stream, awhh, xwb, hT);
    }

    hipLaunchKernelGGL(k3_fc, dim3(64), dim3(256), 0, stream, hT, Wfc, bfc, out);
}

// Round 3
// 835.267 us; speedup vs baseline: 1.7920x; 1.0437x over previous
//
#include <hip/hip_runtime.h>
#include <hip/hip_bf16.h>

// RNN: emb[x] -> xw GEMM -> 256 sequential tanh steps -> FC.
// All matmuls in f16 MFMA (16x16x32) with f32 accumulate.
// B=64, T=256, H=E=512, O=4.
//
// R3: K2 fully resident W_hh: kc 0..11 in registers (192 VGPR/lane,
// unified VGPR/AGPR file), kc 12..15 in LDS (128 KB). Zero global
// streaming inside the step loop -> MFMA-issue-bound (~2483 cyc/step).
// K1 staging copy made lane-coalesced (was 128B-strided per lane).

typedef _Float16 f16;
typedef _Float16 f16x4 __attribute__((ext_vector_type(4)));
typedef _Float16 f16x8 __attribute__((ext_vector_type(8)));
typedef float    f32x4 __attribute__((ext_vector_type(4)));

#define BSZ 64
#define TSZ 256
#define HSZ 512

// d_ws layout (bytes)
#define XWB_OFF   0u
#define XWB_BYTES (64u*256u*512u*2u)            // 16 MB: xw + b_ih + b_hh, f16 [B*T][H]
#define AWHH_OFF  (XWB_OFF + XWB_BYTES)         // 512 KB: W_hh A-operand fragments
#define BWIH_OFF  (AWHH_OFF + 512u*1024u)       // 512 KB: W_ih B-operand fragments
#define HT_OFF    (BWIH_OFF + 512u*1024u)       // 128 KB: final hidden state f32 [B][H]

// ---------------------------------------------------------------------------
// K0: pack W_hh (A-operand layout) and W_ih (B-operand layout) into
// fragment-linear f16: frag (kc, tile) at ((kc*32 + tile)*64 + lane)*8 f16.
// ---------------------------------------------------------------------------
__global__ __launch_bounds__(64) void k0_prep(const float* __restrict__ Whh,
                                              const float* __restrict__ Wih,
                                              f16* __restrict__ awhh,
                                              f16* __restrict__ bwih) {
    int id   = blockIdx.x;           // 0..1023
    int lane = threadIdx.x;          // 0..63
    bool is_ih = id >= 512;
    int lid = is_ih ? (id - 512) : id;       // = kc*32 + tile
    const float* src = is_ih ? Wih : Whh;
    f16* dst = is_ih ? bwih : awhh;
    int tile = lid & 31;
    int kc   = lid >> 5;
    int row  = tile * 16 + (lane & 15);
    int col0 = kc * 32 + (lane >> 4) * 8;
    const float* p = src + (size_t)row * 512 + col0;
    float4 v0 = *(const float4*)(p);
    float4 v1 = *(const float4*)(p + 4);
    f16x8 o;
    o[0] = (f16)v0.x; o[1] = (f16)v0.y; o[2] = (f16)v0.z; o[3] = (f16)v0.w;
    o[4] = (f16)v1.x; o[5] = (f16)v1.y; o[6] = (f16)v1.z; o[7] = (f16)v1.w;
    *(f16x8*)(dst + (size_t)lid * 512 + lane * 8) = o;
}

// ---------------------------------------------------------------------------
// K1: xwb[m][n] = sum_k emb[x[m]][k] * W_ih[n][k] + b_ih[n] + b_hh[n], f16.
// Staging copy is lane-coalesced (q*256+tid): 16 B/lane, consecutive lanes
// consecutive addresses. (R2 had tid*8+q: 128-B lane stride, uncoalesced.)
// ---------------------------------------------------------------------------
__global__ __launch_bounds__(256) void k1_xw(const int* __restrict__ x,
                                             const float* __restrict__ emb,
                                             const float* __restrict__ bih,
                                             const float* __restrict__ bhh,
                                             const f16* __restrict__ bwih,
                                             f16* __restrict__ xwb) {
    __shared__ f16 Bs[32 * 512];     // 32 KB: one k-chunk of B fragments
    int tid  = threadIdx.x;
    int wave = tid >> 6, lane = tid & 63;
    int quad = lane >> 4, l15 = lane & 15;
    int mrow0 = blockIdx.x * 64 + wave * 16;

    int arow_idx = x[mrow0 + l15];                  // gathered embedding row
    const float* arow = emb + (size_t)arow_idx * 512;

    f32x4 acc[32];
#pragma unroll
    for (int nt = 0; nt < 32; ++nt) acc[nt] = (f32x4){0.f, 0.f, 0.f, 0.f};

    for (int kc = 0; kc < 16; ++kc) {
        __syncthreads();   // protect previous iteration's LDS reads
        {   // stage 32 KB of B frags: coalesced copy
            const float4* s4 = (const float4*)(bwih + (size_t)kc * 16384);
            float4* d4 = (float4*)Bs;
#pragma unroll
            for (int q = 0; q < 8; ++q) d4[q * 256 + tid] = s4[q * 256 + tid];
        }
        __syncthreads();

        float4 a0 = *(const float4*)(arow + kc * 32 + quad * 8);
        float4 a1 = *(const float4*)(arow + kc * 32 + quad * 8 + 4);
        f16x8 af;
        af[0] = (f16)a0.x; af[1] = (f16)a0.y; af[2] = (f16)a0.z; af[3] = (f16)a0.w;
        af[4] = (f16)a1.x; af[5] = (f16)a1.y; af[6] = (f16)a1.z; af[7] = (f16)a1.w;

#pragma unroll
        for (int nt = 0; nt < 32; ++nt) {
            f16x8 bf = *(const f16x8*)(Bs + nt * 512 + lane * 8);
            acc[nt] = __builtin_amdgcn_mfma_f32_16x16x32_f16(af, bf, acc[nt], 0, 0, 0);
        }
    }

    // Epilogue: D col n = l15 (+16*nt), D row = quad*4 + r. Fold both biases.
#pragma unroll 4
    for (int nt = 0; nt < 32; ++nt) {
        int n = nt * 16 + l15;
        float bias = bih[n] + bhh[n];
#pragma unroll
        for (int r = 0; r < 4; ++r) {
            int m = mrow0 + quad * 4 + r;
            xwb[(size_t)m * 512 + n] = (f16)(acc[nt][r] + bias);
        }
    }
}

// ---------------------------------------------------------------------------
// K2 (big-LDS): 16 WGs x 512 threads; WG owns batches wg*4..wg*4+3.
// Per step: D[i][b] = sum_j W_hh[i][j] * h[b][j]; + xwb; tanh.
// Wave w owns m-tiles 4w..4w+3. W_hh residency:
//   kc 0..11 -> VGPR-persistent areg[4][12] (192 regs/lane, unified file)
//   kc 12..15 -> LDS fragS (128 KB)
// No global loads in the step loop except the xw prefetch (masked, 8 B/lane).
// h double-buffered in LDS, row stride 544 f16 (2-way bank alias = free).
// ---------------------------------------------------------------------------
__global__ __launch_bounds__(512, 2) void k2_rnn_big(const f16* __restrict__ awhh,
                                                     const f16* __restrict__ xwb,
                                                     float* __restrict__ hT) {
    extern __shared__ char smem[];
    f16* fragS = (f16*)smem;                               // 131072 B
    f16* hbuf  = (f16*)(smem + 131072);                    // 2*4*544 f16 = 8704 B

    int tid  = threadIdx.x;
    int wave = tid >> 6, lane = tid & 63;
    int quad = lane >> 4, n = lane & 15;
    int mtb  = wave * 4;
    int b    = blockIdx.x * 4 + n;               // valid only when n < 4

    // --- persistent A-frags, kc 0..11 ---
    f16x8 areg[4][12];
#pragma unroll
    for (int p = 0; p < 4; ++p)
#pragma unroll
        for (int kc = 0; kc < 12; ++kc)
            areg[p][kc] = *(const f16x8*)(awhh +
                ((size_t)(kc * 32 + mtb + p) * 64 + lane) * 8);

    // --- LDS-resident frags, kc 12..15 (per-wave private region) ---
#pragma unroll
    for (int p = 0; p < 4; ++p)
#pragma unroll
        for (int j = 0; j < 4; ++j) {
            f16x8 v = *(const f16x8*)(awhh +
                ((size_t)((12 + j) * 32 + mtb + p) * 64 + lane) * 8);
            *(f16x8*)(fragS + (((mtb + p) * 4 + j) * 64 + lane) * 8) = v;
        }

    // --- zero h double-buffer ---
    {
        unsigned int* hz = (unsigned int*)hbuf;
        for (int i = tid; i < 2176; i += 512) hz[i] = 0u;
    }
    __syncthreads();

    const f16* xwb_b = xwb + (size_t)b * 256 * 512;   // deref'd only when n<4

    for (int t = 0; t < 256; ++t) {
        const f16* hc = hbuf + (size_t)(t & 1) * 4 * 544;
        f16*       hn = hbuf + (size_t)((t + 1) & 1) * 4 * 544;

        // prefetch xw for this step (h-independent -> latency hidden by MFMAs)
        f16x4 xw4[4];
        if (n < 4) {
#pragma unroll
            for (int p = 0; p < 4; ++p)
                xw4[p] = *(const f16x4*)(xwb_b + (size_t)t * 512 +
                                         (mtb + p) * 16 + quad * 4);
        }

        f32x4 acc[4];
#pragma unroll
        for (int p = 0; p < 4; ++p) acc[p] = (f32x4){0.f, 0.f, 0.f, 0.f};

        // kc 0..11: A from registers; only a masked 16-lane bf read per kc.
#pragma unroll
        for (int kc = 0; kc < 12; ++kc) {
            f16x8 bf = {};
            if (n < 4)
                bf = *(const f16x8*)(hc + n * 544 + kc * 32 + quad * 8);
#pragma unroll
            for (int p = 0; p < 4; ++p)
                acc[p] = __builtin_amdgcn_mfma_f32_16x16x32_f16(
                    areg[p][kc], bf, acc[p], 0, 0, 0);
        }

        // kc 12..15: A from LDS.
#pragma unroll
        for (int j = 0; j < 4; ++j) {
            int kc = 12 + j;
            f16x8 bf = {};
            if (n < 4)
                bf = *(const f16x8*)(hc + n * 544 + kc * 32 + quad * 8);
#pragma unroll
            for (int p = 0; p < 4; ++p) {
                f16x8 af = *(const f16x8*)(fragS +
                    (((mtb + p) * 4 + j) * 64 + lane) * 8);
                acc[p] = __builtin_amdgcn_mfma_f32_16x16x32_f16(
                    af, bf, acc[p], 0, 0, 0);
            }
        }

        if (n < 4) {
#pragma unroll
            for (int p = 0; p < 4; ++p) {
                int i0 = (mtb + p) * 16 + quad * 4;
                f16x4 hv;
                f32x4 hf;
#pragma unroll
                for (int r = 0; r < 4; ++r) {
                    float z = acc[p][r] + (float)xw4[p][r];
                    float e = __expf(2.f * z);       // bounded: |z| small
                    float th = (e - 1.f) / (e + 1.f);
                    hv[r] = (f16)th;
                    hf[r] = th;
                }
                *(f16x4*)(hn + n * 544 + i0) = hv;
                if (t == 255) *(f32x4*)(hT + (size_t)b * 512 + i0) = hf;
            }
        }
        __syncthreads();   // h(t+1) fully written before next step reads it
    }
}

// ---------------------------------------------------------------------------
// K2 fallback (64-KB-safe, R2 structure): areg 8 kc, fragS 1 kc, stream 7 kc.
// ---------------------------------------------------------------------------
__global__ __launch_bounds__(512, 2) void k2_rnn_small(const f16* __restrict__ awhh,
                                                       const f16* __restrict__ xwb,
                                                       float* __restrict__ hT) {
    constexpr int LKC = 1, SKC = 7;
    extern __shared__ char smem[];
    f16* fragS = (f16*)smem;                               // 32 KB
    f16* hbuf  = (f16*)(smem + 32768);                     // 8704 B

    int tid  = threadIdx.x;
    int wave = tid >> 6, lane = tid & 63;
    int quad = lane >> 4, n = lane & 15;
    int mtb  = wave * 4;
    int b    = blockIdx.x * 4 + n;

    f16x8 areg[4][8];
#pragma unroll
    for (int p = 0; p < 4; ++p)
#pragma unroll
        for (int kc = 0; kc < 8; ++kc)
            areg[p][kc] = *(const f16x8*)(awhh +
                ((size_t)(kc * 32 + mtb + p) * 64 + lane) * 8);

#pragma unroll
    for (int p = 0; p < 4; ++p)
        for (int j = 0; j < LKC; ++j) {
            f16x8 v = *(const f16x8*)(awhh +
                ((size_t)((8 + j) * 32 + mtb + p) * 64 + lane) * 8);
            *(f16x8*)(fragS + (((mtb + p) * LKC + j) * 64 + lane) * 8) = v;
        }

    {
        unsigned int* hz = (unsigned int*)hbuf;
        for (int i = tid; i < 2176; i += 512) hz[i] = 0u;
    }
    __syncthreads();

    const f16* xwb_b = xwb + (size_t)b * 256 * 512;

    for (int t = 0; t < 256; ++t) {
        const f16* hc = hbuf + (size_t)(t & 1) * 4 * 544;
        f16*       hn = hbuf + (size_t)((t + 1) & 1) * 4 * 544;

        f16x4 xw4[4];
        if (n < 4) {
#pragma unroll
            for (int p = 0; p < 4; ++p)
                xw4[p] = *(const f16x4*)(xwb_b + (size_t)t * 512 +
                                         (mtb + p) * 16 + quad * 4);
        }

        f16x8 sbuf[3][4];
#pragma unroll
        for (int q = 0; q < 3; ++q)
#pragma unroll
            for (int p = 0; p < 4; ++p)
                sbuf[q][p] = *(const f16x8*)(awhh +
                    ((size_t)((8 + LKC + q) * 32 + mtb + p) * 64 + lane) * 8);

        f32x4 acc[4];
#pragma unroll
        for (int p = 0; p < 4; ++p) acc[p] = (f32x4){0.f, 0.f, 0.f, 0.f};

#pragma unroll
        for (int kc = 0; kc < 16; ++kc) {
            f16x8 bf = {};
            if (n < 4)
                bf = *(const f16x8*)(hc + n * 544 + kc * 32 + quad * 8);

            if (kc < 8) {
#pragma unroll
                for (int p = 0; p < 4; ++p)
                    acc[p] = __builtin_amdgcn_mfma_f32_16x16x32_f16(
                        areg[p][kc], bf, acc[p], 0, 0, 0);
            } else if (kc < 8 + LKC) {
                int j = kc - 8;
#pragma unroll
                for (int p = 0; p < 4; ++p) {
                    f16x8 af = *(const f16x8*)(fragS +
                        (((mtb + p) * LKC + j) * 64 + lane) * 8);
                    acc[p] = __builtin_amdgcn_mfma_f32_16x16x32_f16(
                        af, bf, acc[p], 0, 0, 0);
                }
            } else {
                int q = kc - 8 - LKC;
#pragma unroll
                for (int p = 0; p < 4; ++p)
                    acc[p] = __builtin_amdgcn_mfma_f32_16x16x32_f16(
                        sbuf[q % 3][p], bf, acc[p], 0, 0, 0);
                if (q + 3 < SKC) {
#pragma unroll
                    for (int p = 0; p < 4; ++p)
                        sbuf[(q + 3) % 3][p] = *(const f16x8*)(awhh +
                            ((size_t)((8 + LKC + q + 3) * 32 + mtb + p) * 64 + lane) * 8);
                }
            }
        }

        if (n < 4) {
#pragma unroll
            for (int p = 0; p < 4; ++p) {
                int i0 = (mtb + p) * 16 + quad * 4;
                f16x4 hv;
                f32x4 hf;
#pragma unroll
                for (int r = 0; r < 4; ++r) {
                    float z = acc[p][r] + (float)xw4[p][r];
                    float e = __expf(2.f * z);
                    float th = (e - 1.f) / (e + 1.f);
                    hv[r] = (f16)th;
                    hf[r] = th;
                }
                *(f16x4*)(hn + n * 544 + i0) = hv;
                if (t == 255) *(f32x4*)(hT + (size_t)b * 512 + i0) = hf;
            }
        }
        __syncthreads();
    }
}

// ---------------------------------------------------------------------------
// K3: out[b][o] = sum_i hT[b][i] * W_fc[o][i] + b_fc[o].
// ---------------------------------------------------------------------------
__global__ __launch_bounds__(256) void k3_fc(const float* __restrict__ hT,
                                             const float* __restrict__ Wfc,
                                             const float* __restrict__ bfc,
                                             float* __restrict__ out) {
    int b = blockIdx.x;
    int o = threadIdx.x >> 6, lane = threadIdx.x & 63;
    float s = 0.f;
#pragma unroll
    for (int c = 0; c < 8; ++c) {
        int i = c * 64 + lane;
        s += hT[(size_t)b * 512 + i] * Wfc[(size_t)o * 512 + i];
    }
#pragma unroll
    for (int off = 32; off > 0; off >>= 1) s += __shfl_down(s, off, 64);
    if (lane == 0) out[b * 4 + o] = s + bfc[o];
}

extern "C" void kernel_launch(void* const* d_in, const int* in_sizes, int n_in,
                              void* d_out, int out_size, void* d_ws, size_t ws_size,
                              hipStream_t stream) {
    const int*   x   = (const int*)d_in[0];
    const float* emb = (const float*)d_in[1];
    const float* Wih = (const float*)d_in[2];
    const float* Whh = (const float*)d_in[3];
    const float* bih = (const float*)d_in[4];
    const float* bhh = (const float*)d_in[5];
    const float* Wfc = (const float*)d_in[6];
    const float* bfc = (const float*)d_in[7];
    float* out = (float*)d_out;

    char* ws = (char*)d_ws;
    f16*   xwb  = (f16*)(ws + XWB_OFF);
    f16*   awhh = (f16*)(ws + AWHH_OFF);
    f16*   bwih = (f16*)(ws + BWIH_OFF);
    float* hT   = (float*)(ws + HT_OFF);

    hipLaunchKernelGGL(k0_prep, dim3(1024), dim3(64),  0, stream, Whh, Wih, awhh, bwih);
    hipLaunchKernelGGL(k1_xw,   dim3(256),  dim3(256), 0, stream, x, emb, bih, bhh, bwih, xwb);

    const int LDS_BIG   = 131072 + 8704;      // 139776
    const int LDS_SMALL = 32768 + 8704;       // 41472
    int dev = 0;
    (void)hipGetDevice(&dev);
    int maxlds = 0;
    (void)hipDeviceGetAttribute(&maxlds, hipDeviceAttributeMaxSharedMemoryPerBlock, dev);
    bool big = maxlds >= LDS_BIG;
    if (big)
        big = (hipFuncSetAttribute((const void*)&k2_rnn_big,
                                   hipFuncAttributeMaxDynamicSharedMemorySize,
                                   LDS_BIG) == hipSuccess);
    if (big) {
        hipLaunchKernelGGL(k2_rnn_big, dim3(16), dim3(512), LDS_BIG, stream, awhh, xwb, hT);
    } else {
        hipLaunchKernelGGL(k2_rnn_small, dim3(16), dim3(512), LDS_SMALL, stream, awhh, xwb, hT);
    }

    hipLaunchKernelGGL(k3_fc, dim3(64), dim3(256), 0, stream, hT, Wfc, bfc, out);
}